// Round 4
// baseline (409.086 us; speedup 1.0000x reference)
//
#include <hip/hip_runtime.h>
#include <hip/hip_bf16.h>

typedef __hip_bfloat16 bf16;
typedef short v8s __attribute__((ext_vector_type(8)));   // 8 bf16 = 16B
typedef float v4f __attribute__((ext_vector_type(4)));   // MFMA accumulator

#define BB   4
#define NN   1024
#define DD   512
#define NHH  8
#define DH   64

#define MFMA(a, b, c) __builtin_amdgcn_mfma_f32_16x16x32_bf16(a, b, c, 0, 0, 0)

__device__ __forceinline__ void split2(float v, bf16& hi, bf16& lo) {
    hi = __float2bfloat16(v);
    lo = __float2bfloat16(v - __bfloat162float(hi));
}

__device__ __forceinline__ short f2bf_bits(float f) {
    bf16 h = __float2bfloat16(f);
    short s;
    __builtin_memcpy(&s, &h, 2);
    return s;
}

// ---------------------------------------------------------------------------
// K1: LayerNorm (f32 in) -> split bf16 hi/lo. One block per row, 256 thr.
// ---------------------------------------------------------------------------
__global__ __launch_bounds__(256) void ln_split_kernel(
    const float* __restrict__ x, const float* __restrict__ gamma,
    const float* __restrict__ beta,
    bf16* __restrict__ c_hi, bf16* __restrict__ c_lo)
{
    int row = blockIdx.x;
    int t = threadIdx.x;
    const float* xr = x + (size_t)row * DD;
    float v0 = xr[2 * t];
    float v1 = xr[2 * t + 1];
    float s = v0 + v1;
    float sq = v0 * v0 + v1 * v1;
#pragma unroll
    for (int o = 32; o; o >>= 1) {
        s  += __shfl_down(s, o, 64);
        sq += __shfl_down(sq, o, 64);
    }
    __shared__ float red[8];
    __shared__ float mb[2];
    int wave = t >> 6, lane = t & 63;
    if (lane == 0) { red[wave] = s; red[4 + wave] = sq; }
    __syncthreads();
    if (t == 0) {
        float S  = red[0] + red[1] + red[2] + red[3];
        float SQ = red[4] + red[5] + red[6] + red[7];
        float mean = S * (1.0f / DD);
        float var  = SQ * (1.0f / DD) - mean * mean;
        mb[0] = mean;
        mb[1] = rsqrtf(var + 1e-5f);
    }
    __syncthreads();
    float mean = mb[0], rstd = mb[1];
    float y0 = (v0 - mean) * rstd * gamma[2 * t] + beta[2 * t];
    float y1 = (v1 - mean) * rstd * gamma[2 * t + 1] + beta[2 * t + 1];
    bf16 h, l;
    split2(y0, h, l);
    c_hi[(size_t)row * DD + 2 * t]     = h;
    c_lo[(size_t)row * DD + 2 * t]     = l;
    split2(y1, h, l);
    c_hi[(size_t)row * DD + 2 * t + 1] = h;
    c_lo[(size_t)row * DD + 2 * t + 1] = l;
}

// ---------------------------------------------------------------------------
// K2: weight conversions. z=0: Wq->hi/lo; z=1: Wk->hi/lo; z=2: Wv->bf16.
// ---------------------------------------------------------------------------
__global__ __launch_bounds__(256) void convert_kernel(
    const float* __restrict__ Wq, const float* __restrict__ Wk,
    const float* __restrict__ Wv,
    bf16* __restrict__ wq_hi, bf16* __restrict__ wq_lo,
    bf16* __restrict__ wk_hi, bf16* __restrict__ wk_lo,
    bf16* __restrict__ wv_bf)
{
    int z = blockIdx.z;
    int i4 = (blockIdx.x * 256 + threadIdx.x) * 4;
    if (i4 >= DD * DD) return;
    const float* src = (z == 0) ? Wq : (z == 1) ? Wk : Wv;
    float4 v = *(const float4*)(src + i4);
    float vv[4] = {v.x, v.y, v.z, v.w};
    if (z == 2) {
#pragma unroll
        for (int j = 0; j < 4; ++j) wv_bf[i4 + j] = __float2bfloat16(vv[j]);
    } else {
        bf16* dh = (z == 0) ? wq_hi : wk_hi;
        bf16* dl = (z == 0) ? wq_lo : wk_lo;
#pragma unroll
        for (int j = 0; j < 4; ++j) {
            bf16 h, l;
            split2(vv[j], h, l);
            dh[i4 + j] = h;
            dl[i4 + j] = l;
        }
    }
}

// ---------------------------------------------------------------------------
// K3: q & k projections fused (shared A). 16-row blocks (grid 256).
// Full K-strip of c_hi/c_lo staged ONCE in LDS ([c8][row] 16B blocks,
// row XOR-swizzled by c8 for conflict-free access both directions).
// Col loop: 4 iters x (4 waves x 32 cols). 3-MFMA split precision.
// ---------------------------------------------------------------------------
__global__ __launch_bounds__(256) void qk_proj_kernel(
    const bf16* __restrict__ c_hi, const bf16* __restrict__ c_lo,
    const bf16* __restrict__ wq_hi, const bf16* __restrict__ wq_lo,
    const bf16* __restrict__ wk_hi, const bf16* __restrict__ wk_lo,
    const float* __restrict__ bq, const float* __restrict__ bk,
    bf16* __restrict__ q_hi, bf16* __restrict__ q_lo,
    bf16* __restrict__ k_hi, bf16* __restrict__ k_lo)
{
    __shared__ v8s Ah[64 * 16];   // 16 KB, [c8][r^ (c8&15)]
    __shared__ v8s Al[64 * 16];   // 16 KB
    int tid = threadIdx.x;
    int rb = blockIdx.x;          // rows [rb*16, rb*16+16)
    int lane = tid & 63, wave = tid >> 6;
    int lr = lane & 15, lq = lane >> 4;

#pragma unroll
    for (int j = 0; j < 4; ++j) {
        int idx = j * 256 + tid;
        int c8 = idx & 63, r = idx >> 6;
        int slot = c8 * 16 + (r ^ (c8 & 15));
        size_t go = (size_t)(rb * 16 + r) * DD + c8 * 8;
        Ah[slot] = *(const v8s*)(c_hi + go);
        Al[slot] = *(const v8s*)(c_lo + go);
    }
    __syncthreads();

    for (int cb = 0; cb < 4; ++cb) {
        int c0 = cb * 128 + wave * 32;
        v4f aq[2] = {}, ak[2] = {};
        for (int d0 = 0; d0 < DD; d0 += 32) {
            int c8 = (d0 >> 3) + lq;
            v8s ah = Ah[c8 * 16 + (lr ^ (c8 & 15))];
            v8s al = Al[c8 * 16 + (lr ^ (c8 & 15))];
#pragma unroll
            for (int ct = 0; ct < 2; ++ct) {
                size_t wo = (size_t)(c0 + ct * 16 + lr) * DD + d0 + lq * 8;
                v8s qh = *(const v8s*)(wq_hi + wo);
                v8s ql = *(const v8s*)(wq_lo + wo);
                v8s kh = *(const v8s*)(wk_hi + wo);
                v8s kl = *(const v8s*)(wk_lo + wo);
                aq[ct] = MFMA(ah, qh, aq[ct]);
                aq[ct] = MFMA(al, qh, aq[ct]);
                aq[ct] = MFMA(ah, ql, aq[ct]);
                ak[ct] = MFMA(ah, kh, ak[ct]);
                ak[ct] = MFMA(al, kh, ak[ct]);
                ak[ct] = MFMA(ah, kl, ak[ct]);
            }
        }
#pragma unroll
        for (int ct = 0; ct < 2; ++ct) {
            int col = c0 + ct * 16 + lr;
            float bqq = bq[col], bkk = bk[col];
#pragma unroll
            for (int r = 0; r < 4; ++r) {
                int row = rb * 16 + lq * 4 + r;
                bf16 h, l;
                split2(aq[ct][r] + bqq, h, l);
                q_hi[(size_t)row * DD + col] = h;
                q_lo[(size_t)row * DD + col] = l;
                split2(ak[ct][r] + bkk, h, l);
                k_hi[(size_t)row * DD + col] = h;
                k_lo[(size_t)row * DD + col] = l;
            }
        }
    }
}

// ---------------------------------------------------------------------------
// K4: v projection (plain bf16), exo f32->bf16 conversion fused into staging.
// Output transposed: vT[b*512+col][n].
// ---------------------------------------------------------------------------
__global__ __launch_bounds__(256) void v_proj_kernel(
    const float* __restrict__ exo, const bf16* __restrict__ wv_bf,
    const float* __restrict__ bv, bf16* __restrict__ vT)
{
    __shared__ v8s Ah[64 * 16];   // 16 KB
    int tid = threadIdx.x;
    int rb = blockIdx.x;
    int lane = tid & 63, wave = tid >> 6;
    int lr = lane & 15, lq = lane >> 4;

#pragma unroll
    for (int j = 0; j < 4; ++j) {
        int idx = j * 256 + tid;
        int c8 = idx & 63, r = idx >> 6;
        int slot = c8 * 16 + (r ^ (c8 & 15));
        size_t go = (size_t)(rb * 16 + r) * DD + c8 * 8;
        float4 f0 = *(const float4*)(exo + go);
        float4 f1 = *(const float4*)(exo + go + 4);
        v8s a;
        a[0] = f2bf_bits(f0.x); a[1] = f2bf_bits(f0.y);
        a[2] = f2bf_bits(f0.z); a[3] = f2bf_bits(f0.w);
        a[4] = f2bf_bits(f1.x); a[5] = f2bf_bits(f1.y);
        a[6] = f2bf_bits(f1.z); a[7] = f2bf_bits(f1.w);
        Ah[slot] = a;
    }
    __syncthreads();

    for (int cb = 0; cb < 4; ++cb) {
        int c0 = cb * 128 + wave * 32;
        v4f acc[2] = {};
        for (int d0 = 0; d0 < DD; d0 += 32) {
            int c8 = (d0 >> 3) + lq;
            v8s ah = Ah[c8 * 16 + (lr ^ (c8 & 15))];
#pragma unroll
            for (int ct = 0; ct < 2; ++ct) {
                v8s wb = *(const v8s*)(wv_bf + (size_t)(c0 + ct * 16 + lr) * DD + d0 + lq * 8);
                acc[ct] = MFMA(ah, wb, acc[ct]);
            }
        }
#pragma unroll
        for (int ct = 0; ct < 2; ++ct) {
            int col = c0 + ct * 16 + lr;
            float bvv = bv[col];
#pragma unroll
            for (int r = 0; r < 4; ++r) {
                int row = rb * 16 + lq * 4 + r;
                int b_ = row >> 10, n = row & (NN - 1);
                vT[((size_t)b_ * DD + col) * NN + n] =
                    __float2bfloat16(acc[ct][r] + bvv);
            }
        }
    }
}

// ---------------------------------------------------------------------------
// K5: fused scores^T + softmax + adj + dist-write + PV + att-write.
// Block = (b, h, 16 q-rows). Computes S^T (A=K, B=Q) so each lane owns
// one q-row (lr) and 64 k-cols -> softmax is 2 shuffles + 16-entry table.
// p packed bf16 into pb[c8][row] (conflict-free both sides), PV from LDS.
// ---------------------------------------------------------------------------
__global__ __launch_bounds__(256) void attn_fused_kernel(
    const bf16* __restrict__ q_hi, const bf16* __restrict__ q_lo,
    const bf16* __restrict__ k_hi, const bf16* __restrict__ k_lo,
    const float* __restrict__ adj, const bf16* __restrict__ vT,
    float* __restrict__ dist, float* __restrict__ att)
{
    __shared__ v8s pb[128 * 16];      // 32 KB: [c8][r], bf16 p values
    __shared__ float redmax[4][16];
    __shared__ float redsum[4][16];
    int i0 = blockIdx.x * 16;
    int h  = blockIdx.y;
    int b  = blockIdx.z;
    int lane = threadIdx.x & 63, wave = threadIdx.x >> 6;
    int lr = lane & 15, lq = lane >> 4;

    size_t qoff  = (size_t)(b * NN + i0 + lr) * DD + h * DH + lq * 8;
    size_t kbase = (size_t)(b * NN + wave * 256 + lr) * DD + h * DH + lq * 8;

    // Phase 1: S^T for k-cols [wave*256, +256) x q-rows [i0, i0+16)
    v4f acc[16] = {};
#pragma unroll
    for (int kk = 0; kk < 2; ++kk) {
        v8s bh = *(const v8s*)(q_hi + qoff + kk * 32);
        v8s bl = *(const v8s*)(q_lo + qoff + kk * 32);
#pragma unroll
        for (int t = 0; t < 16; ++t) {
            size_t ko = kbase + (size_t)t * 16 * DD + kk * 32;
            v8s ah = *(const v8s*)(k_hi + ko);
            v8s al = *(const v8s*)(k_lo + ko);
            acc[t] = MFMA(ah, bh, acc[t]);
            acc[t] = MFMA(al, bh, acc[t]);
            acc[t] = MFMA(ah, bl, acc[t]);
        }
    }

    // Phase 2: softmax along k (lane-local 64 vals + xor16/32 + wave table)
    const float scale = 0.04419417382415922f;  // 1/sqrt(512)
    float mx = -1e30f;
#pragma unroll
    for (int t = 0; t < 16; ++t)
#pragma unroll
        for (int r = 0; r < 4; ++r) mx = fmaxf(mx, acc[t][r]);
    mx = fmaxf(mx, __shfl_xor(mx, 16, 64));
    mx = fmaxf(mx, __shfl_xor(mx, 32, 64));
    if (lane < 16) redmax[wave][lane] = mx;
    __syncthreads();
    float m_all = fmaxf(fmaxf(redmax[0][lr], redmax[1][lr]),
                        fmaxf(redmax[2][lr], redmax[3][lr])) * scale;
    float ssum = 0.0f;
#pragma unroll
    for (int t = 0; t < 16; ++t)
#pragma unroll
        for (int r = 0; r < 4; ++r) {
            float e = __expf(acc[t][r] * scale - m_all);
            acc[t][r] = e;
            ssum += e;
        }
    ssum += __shfl_xor(ssum, 16, 64);
    ssum += __shfl_xor(ssum, 32, 64);
    if (lane < 16) redsum[wave][lane] = ssum;
    __syncthreads();
    float inv = 1.0f / (redsum[0][lr] + redsum[1][lr] +
                        redsum[2][lr] + redsum[3][lr]);

    const float* arow = adj + (size_t)(i0 + lr) * NN + wave * 256 + lq * 4;
    float* drow = dist + ((size_t)((b * NHH + h) * NN) + i0 + lr) * NN
                       + wave * 256 + lq * 4;
#pragma unroll
    for (int t = 0; t < 16; ++t) {
        float4 av = *(const float4*)(arow + t * 16);
        float4 pv;
        pv.x = acc[t][0] * inv * av.x;
        pv.y = acc[t][1] * inv * av.y;
        pv.z = acc[t][2] * inv * av.z;
        pv.w = acc[t][3] * inv * av.w;
        *(float4*)(drow + t * 16) = pv;
        // pack 4 bf16 (8B) into pb
        short pk[4];
        pk[0] = f2bf_bits(pv.x); pk[1] = f2bf_bits(pv.y);
        pk[2] = f2bf_bits(pv.z); pk[3] = f2bf_bits(pv.w);
        int c8 = wave * 32 + 2 * t + (lq >> 1);
        char* dst = (char*)&pb[c8 * 16 + lr] + (lq & 1) * 8;
        __builtin_memcpy(dst, pk, 8);
    }
    __syncthreads();

    // Phase 3: PV. wave = dh-tile [wave*16, +16), k-loop over all 1024 m.
    size_t vbase = (size_t)(b * DD + h * DH + wave * 16 + lr) * NN + lq * 8;
    v4f o = {};
    for (int m0 = 0; m0 < NN; m0 += 32) {
        int c8 = (m0 >> 3) + lq;
        v8s a = pb[c8 * 16 + lr];
        v8s bb = *(const v8s*)(vT + vbase + m0);
        o = MFMA(a, bb, o);
    }
#pragma unroll
    for (int r = 0; r < 4; ++r)
        att[(size_t)(b * NN + i0 + lq * 4 + r) * DD + h * DH + wave * 16 + lr] = o[r];
}

// ---------------------------------------------------------------------------
extern "C" void kernel_launch(void* const* d_in, const int* in_sizes, int n_in,
                              void* d_out, int out_size, void* d_ws, size_t ws_size,
                              hipStream_t stream)
{
    const float* user_exo = (const float*)d_in[0];
    const float* exo      = (const float*)d_in[1];
    const float* adj      = (const float*)d_in[2];
    const float* Wq       = (const float*)d_in[3];
    const float* bq       = (const float*)d_in[4];
    const float* Wk       = (const float*)d_in[5];
    const float* bk       = (const float*)d_in[6];
    const float* Wv       = (const float*)d_in[7];
    const float* bv       = (const float*)d_in[8];
    const float* gamma    = (const float*)d_in[9];
    const float* beta     = (const float*)d_in[10];

    float* att  = (float*)d_out;                     // [4,1024,512] f32
    float* dist = att + (size_t)BB * NN * DD;        // [4,8,1024,1024] f32

    const size_t NE = (size_t)BB * NN * DD;          // 2M elems
    const size_t WE = (size_t)DD * DD;               // 256K elems
    bf16* p = (bf16*)d_ws;
    bf16* c_hi   = p; p += NE;
    bf16* c_lo   = p; p += NE;
    bf16* q_hi   = p; p += NE;
    bf16* q_lo   = p; p += NE;
    bf16* k_hi   = p; p += NE;
    bf16* k_lo   = p; p += NE;
    bf16* vT     = p; p += NE;                       // [4,512,1024]
    bf16* wq_hi  = p; p += WE;
    bf16* wq_lo  = p; p += WE;
    bf16* wk_hi  = p; p += WE;
    bf16* wk_lo  = p; p += WE;
    bf16* wv_bf  = p; p += WE;

    ln_split_kernel<<<BB * NN, 256, 0, stream>>>(user_exo, gamma, beta, c_hi, c_lo);
    convert_kernel<<<dim3((DD * DD / 4 + 255) / 256, 1, 3), 256, 0, stream>>>(
        Wq, Wk, Wv, wq_hi, wq_lo, wk_hi, wk_lo, wv_bf);
    qk_proj_kernel<<<BB * NN / 16, 256, 0, stream>>>(
        c_hi, c_lo, wq_hi, wq_lo, wk_hi, wk_lo, bq, bk,
        q_hi, q_lo, k_hi, k_lo);
    v_proj_kernel<<<BB * NN / 16, 256, 0, stream>>>(exo, wv_bf, bv, vT);
    attn_fused_kernel<<<dim3(NN / 16, NHH, BB), 256, 0, stream>>>(
        q_hi, q_lo, k_hi, k_lo, adj, vT, dist, att);
}